// Round 4
// baseline (197.438 us; speedup 1.0000x reference)
//
#include <hip/hip_runtime.h>

// Problem constants
#define BSZ 16
#define NN  128
#define HH  256
#define LLG 9
#define FFE 48   // edge feature dim (padded to 64 for MFMA K)
#define JC  64   // j-chunk size (2 chunks of 64)

typedef float        f32x4 __attribute__((ext_vector_type(4)));
typedef _Float16     f16x8 __attribute__((ext_vector_type(8)));
typedef unsigned int u32x4 __attribute__((ext_vector_type(4)));

static __device__ __forceinline__ unsigned short f2h_bits(float x) {
    _Float16 h = (_Float16)x;   // RNE
    return __builtin_bit_cast(unsigned short, h);
}

static __device__ __forceinline__ float fast_silu(float x) {
    float e = __builtin_amdgcn_exp2f(x * -1.44269504088896341f);
    return x * __builtin_amdgcn_rcpf(1.0f + e);
}

// ---------------------------------------------------------------------------
// Kernel 1: weight transpose + f32->f16 convert.  (proven round-1/2 version)
//   WeT[h][f]  (256 x 64, f>=48 zero-padded)  from W1 rows 521..568
//   W2T[ho][k] (256 x 256)                    from W2[k][ho]
// ---------------------------------------------------------------------------
__global__ __launch_bounds__(256) void pre_w(
    const float* __restrict__ W1, const float* __restrict__ W2,
    unsigned short* __restrict__ W2T, unsigned short* __restrict__ WeT)
{
    int tid = blockIdx.x * 256 + threadIdx.x;   // grid 256 -> 65536 threads
    {
        int ho = tid >> 8, k = tid & 255;
        W2T[(ho << 8) + k] = f2h_bits(W2[(k << 8) + ho]);  // coalesced write
    }
    if (tid < 256 * 64) {
        int h = tid >> 6, f = tid & 63;
        WeT[(h << 6) + f] = (f < FFE) ? f2h_bits(W1[(521 + f) * HH + h])
                                      : (unsigned short)0;
    }
}

// ---------------------------------------------------------------------------
// Kernel 2: pj[b,r,h] = node[b,r,:] @ Wj ;  base[b,r,h] = node@Wi + graph@Wg + b1
// 512 blocks, 4 node rows each.  (proven round-2 version)
// ---------------------------------------------------------------------------
__global__ __launch_bounds__(256) void pre_pjbase(
    const float* __restrict__ node, const float* __restrict__ graph,
    const float* __restrict__ W1, const float* __restrict__ b1,
    float* __restrict__ pj, float* __restrict__ base)
{
    __shared__ float nrow[4][HH];
    __shared__ float gsh[LLG];
    const int blk = blockIdx.x;
    const int b = blk >> 5;             // 32 row-groups of 4 per batch
    const int r0 = (blk & 31) << 2;
    const int h = threadIdx.x;

    for (int t = h; t < 4 * HH; t += 256) {
        int r = t >> 8, k = t & 255;
        nrow[r][k] = node[(((size_t)b * NN) + r0 + r) * HH + k];
    }
    if (h < LLG) gsh[h] = graph[b * LLG + h];
    __syncthreads();

    float accj[4] = {0,0,0,0};
    float acci[4] = {0,0,0,0};
    for (int k = 0; k < HH; ++k) {
        float wj = W1[k * HH + h];
        float wi = W1[(k + HH) * HH + h];
        #pragma unroll
        for (int r = 0; r < 4; ++r) {
            float nv = nrow[r][k];
            accj[r] = fmaf(nv, wj, accj[r]);
            acci[r] = fmaf(nv, wi, acci[r]);
        }
    }
    float accg = b1[h];
    #pragma unroll
    for (int l = 0; l < LLG; ++l)
        accg = fmaf(gsh[l], W1[(2 * HH + l) * HH + h], accg);

    #pragma unroll
    for (int r = 0; r < 4; ++r) {
        size_t off = (((size_t)b * NN) + r0 + r) * HH + h;
        pj[off]   = accj[r];
        base[off] = acci[r] + accg;
    }
}

// ---------------------------------------------------------------------------
// Kernel 3: fused main — round-2 structure (proven post-timing-correct),
// with (a) launch_bounds (256,3) instead of (256,4) to avoid the spill
// catastrophe, and (b) GEMM2 split into 2 register-lean passes.
// ---------------------------------------------------------------------------
__global__ __launch_bounds__(256, 3) void fused_msg(
    const float* __restrict__ edge, const float* __restrict__ pj,
    const float* __restrict__ base, const unsigned short* __restrict__ W2T,
    const unsigned short* __restrict__ WeT, const float* __restrict__ b2,
    float* __restrict__ out)
{
    __shared__ unsigned char h1s[JC * HH * 2];   // 32 KB: h1[jc][h] f16, swizzled
    const int tid  = threadIdx.x;
    const int w    = tid >> 6;         // wave 0..3 (owns h-range w*64..)
    const int lane = tid & 63;
    const int q    = lane >> 4;        // quad 0..3
    const int c    = lane & 15;
    const int bi   = blockIdx.x;       // b*128 + i
    const int b    = bi >> 7;

    const float* eb = edge + (size_t)bi * (NN * FFE);

    float b2v[4];
    #pragma unroll
    for (int nt = 0; nt < 4; ++nt) b2v[nt] = b2[(w << 6) + (nt << 4) + c];

    float s[4] = {0.f, 0.f, 0.f, 0.f};

    #pragma unroll 1
    for (int chunk = 0; chunk < 2; ++chunk) {
        // ------------------ GEMM1: D1[h, jc] ------------------
        f32x4 acc1[4][4];
        #pragma unroll
        for (int mt = 0; mt < 4; ++mt)
            #pragma unroll
            for (int nt = 0; nt < 4; ++nt) acc1[mt][nt] = f32x4{0.f, 0.f, 0.f, 0.f};

        #pragma unroll
        for (int kk = 0; kk < 2; ++kk) {
            const int koff = (kk << 5) + (q << 3);   // f offset 0..56
            f16x8 af[4];
            #pragma unroll
            for (int mt = 0; mt < 4; ++mt) {
                const int row = (w << 6) + (mt << 4) + c;       // h
                af[mt] = *reinterpret_cast<const f16x8*>(WeT + (row << 6) + koff);
            }
            #pragma unroll
            for (int nt = 0; nt < 4; ++nt) {
                const int j = (chunk << 6) + (nt << 4) + c;
                f16x8 bf;
                if (koff < FFE) {
                    const float* p = eb + j * FFE + koff;
                    f32x4 x0 = *reinterpret_cast<const f32x4*>(p);
                    f32x4 x1 = *reinterpret_cast<const f32x4*>(p + 4);
                    bf[0] = (_Float16)x0[0]; bf[1] = (_Float16)x0[1];
                    bf[2] = (_Float16)x0[2]; bf[3] = (_Float16)x0[3];
                    bf[4] = (_Float16)x1[0]; bf[5] = (_Float16)x1[1];
                    bf[6] = (_Float16)x1[2]; bf[7] = (_Float16)x1[3];
                } else {
                    u32x4 z = {0u, 0u, 0u, 0u};
                    bf = __builtin_bit_cast(f16x8, z);
                }
                #pragma unroll
                for (int mt = 0; mt < 4; ++mt)
                    acc1[mt][nt] = __builtin_amdgcn_mfma_f32_16x16x32_f16(
                        af[mt], bf, acc1[mt][nt], 0, 0, 0);
            }
        }

        // epilogue 1: z1 -> silu -> f16 -> LDS (swizzle: byte ^= (jc&7)<<4)
        #pragma unroll
        for (int mt = 0; mt < 4; ++mt) {
            const int h0 = (w << 6) + (mt << 4) + (q << 2);
            const f32x4 bb = *reinterpret_cast<const f32x4*>(
                base + ((size_t)bi << 8) + h0);
            #pragma unroll
            for (int nt = 0; nt < 4; ++nt) {
                const int jc = (nt << 4) + c;
                const int j  = (chunk << 6) + jc;
                const f32x4 pjv = *reinterpret_cast<const f32x4*>(
                    pj + (((size_t)b << 7) + j) * HH + h0);
                float s0 = fast_silu(acc1[mt][nt][0] + bb[0] + pjv[0]);
                float s1 = fast_silu(acc1[mt][nt][1] + bb[1] + pjv[1]);
                float s2 = fast_silu(acc1[mt][nt][2] + bb[2] + pjv[2]);
                float s3 = fast_silu(acc1[mt][nt][3] + bb[3] + pjv[3]);
                unsigned int lo = __builtin_bit_cast(unsigned int,
                                    __builtin_amdgcn_cvt_pkrtz(s0, s1));
                unsigned int hi = __builtin_bit_cast(unsigned int,
                                    __builtin_amdgcn_cvt_pkrtz(s2, s3));
                const unsigned int off =
                    (unsigned)(jc << 9) +
                    (((unsigned)(h0 << 1)) ^ ((unsigned)(jc & 7) << 4));
                *reinterpret_cast<uint2*>(&h1s[off]) = make_uint2(lo, hi);
            }
        }
        __syncthreads();

        // ------------------ GEMM2 (2 register-lean passes): D2[jc, ho] ------
        #pragma unroll 1
        for (int pass = 0; pass < 2; ++pass) {
            f32x4 acc2[2][4];
            #pragma unroll
            for (int m = 0; m < 2; ++m)
                #pragma unroll
                for (int nt = 0; nt < 4; ++nt)
                    acc2[m][nt] = f32x4{0.f, 0.f, 0.f, 0.f};

            #pragma unroll 2
            for (int kk = 0; kk < 8; ++kk) {
                f16x8 a2[2];
                #pragma unroll
                for (int m = 0; m < 2; ++m) {
                    const int jc = (((pass << 1) + m) << 4) + c;
                    const unsigned int off = (unsigned)(jc << 9) +
                        (((unsigned)((kk << 6) + (q << 4))) ^
                         ((unsigned)(jc & 7) << 4));
                    a2[m] = *reinterpret_cast<const f16x8*>(&h1s[off]);
                }
                #pragma unroll
                for (int nt = 0; nt < 4; ++nt) {
                    const int ho = (w << 6) + (nt << 4) + c;
                    const f16x8 bw = *reinterpret_cast<const f16x8*>(
                        W2T + (ho << 8) + (kk << 5) + (q << 3));
                    #pragma unroll
                    for (int m = 0; m < 2; ++m)
                        acc2[m][nt] = __builtin_amdgcn_mfma_f32_16x16x32_f16(
                            a2[m], bw, acc2[m][nt], 0, 0, 0);
                }
            }

            // epilogue 2: silu + accumulate j-partial sums
            #pragma unroll
            for (int nt = 0; nt < 4; ++nt)
                #pragma unroll
                for (int m = 0; m < 2; ++m)
                    #pragma unroll
                    for (int r = 0; r < 4; ++r)
                        s[nt] += fast_silu(acc2[m][nt][r] + b2v[nt]);
        }
        if (chunk == 0) __syncthreads();   // protect LDS before next chunk's writes
    }

    // butterfly across quads (j-rows live in q-groups), then store
    #pragma unroll
    for (int nt = 0; nt < 4; ++nt) {
        s[nt] += __shfl_xor(s[nt], 16);
        s[nt] += __shfl_xor(s[nt], 32);
    }
    float v = (q == 0) ? s[0] : (q == 1) ? s[1] : (q == 2) ? s[2] : s[3];
    out[((size_t)bi << 8) + (w << 6) + lane] = v * 0.0078125f;  // /128
}

// ---------------------------------------------------------------------------
extern "C" void kernel_launch(void* const* d_in, const int* in_sizes, int n_in,
                              void* d_out, int out_size, void* d_ws, size_t ws_size,
                              hipStream_t stream)
{
    const float* node  = (const float*)d_in[0];
    const float* edge  = (const float*)d_in[1];
    const float* graph = (const float*)d_in[2];
    const float* W1    = (const float*)d_in[3];
    const float* b1    = (const float*)d_in[4];
    const float* W2    = (const float*)d_in[5];
    const float* b2    = (const float*)d_in[6];
    float* out = (float*)d_out;

    char* ws = (char*)d_ws;
    unsigned short* W2T = (unsigned short*)ws;              // 131072 B
    unsigned short* WeT = (unsigned short*)(ws + 131072);   //  32768 B
    float* pj   = (float*)(ws + 163840);                    // 2 MB
    float* base = (float*)(ws + 163840 + 2097152);          // 2 MB

    pre_w     <<<256, 256, 0, stream>>>(W1, W2, W2T, WeT);
    pre_pjbase<<<512, 256, 0, stream>>>(node, graph, W1, b1, pj, base);
    fused_msg <<<BSZ * NN, 256, 0, stream>>>(edge, pj, base, W2T, WeT, b2, out);
}

// Round 5
// 107.753 us; speedup vs baseline: 1.8323x; 1.8323x over previous
//
#include <hip/hip_runtime.h>

// Problem constants
#define BSZ 16
#define NN  128
#define HH  256
#define LLG 9
#define FFE 48   // edge feature dim (padded to 64 for MFMA K)

typedef float        f32x4 __attribute__((ext_vector_type(4)));
typedef _Float16     f16x8 __attribute__((ext_vector_type(8)));
typedef unsigned int u32x4 __attribute__((ext_vector_type(4)));

static __device__ __forceinline__ unsigned short f2h_bits(float x) {
    _Float16 h = (_Float16)x;   // RNE
    return __builtin_bit_cast(unsigned short, h);
}

static __device__ __forceinline__ float fast_silu(float x) {
    float e = __builtin_amdgcn_exp2f(x * -1.44269504088896341f);
    return x * __builtin_amdgcn_rcpf(1.0f + e);
}

// ---------------------------------------------------------------------------
// Kernel 1: weight transpose + f32->f16 convert.  (proven)
//   WeT[h][f]  (256 x 64, f>=48 zero-padded)  from W1 rows 521..568
//   W2T[ho][k] (256 x 256)                    from W2[k][ho]
// ---------------------------------------------------------------------------
__global__ __launch_bounds__(256) void pre_w(
    const float* __restrict__ W1, const float* __restrict__ W2,
    unsigned short* __restrict__ W2T, unsigned short* __restrict__ WeT)
{
    int tid = blockIdx.x * 256 + threadIdx.x;   // grid 256 -> 65536 threads
    {
        int ho = tid >> 8, k = tid & 255;
        W2T[(ho << 8) + k] = f2h_bits(W2[(k << 8) + ho]);  // coalesced write
    }
    if (tid < 256 * 64) {
        int h = tid >> 6, f = tid & 63;
        WeT[(h << 6) + f] = (f < FFE) ? f2h_bits(W1[(521 + f) * HH + h])
                                      : (unsigned short)0;
    }
}

// ---------------------------------------------------------------------------
// Kernel 2: pj[b,r,h] = node[b,r,:] @ Wj ;  base[b,r,h] = node@Wi + graph@Wg + b1
// 512 blocks, 4 node rows each.  (proven)
// ---------------------------------------------------------------------------
__global__ __launch_bounds__(256) void pre_pjbase(
    const float* __restrict__ node, const float* __restrict__ graph,
    const float* __restrict__ W1, const float* __restrict__ b1,
    float* __restrict__ pj, float* __restrict__ base)
{
    __shared__ float nrow[4][HH];
    __shared__ float gsh[LLG];
    const int blk = blockIdx.x;
    const int b = blk >> 5;             // 32 row-groups of 4 per batch
    const int r0 = (blk & 31) << 2;
    const int h = threadIdx.x;

    for (int t = h; t < 4 * HH; t += 256) {
        int r = t >> 8, k = t & 255;
        nrow[r][k] = node[(((size_t)b * NN) + r0 + r) * HH + k];
    }
    if (h < LLG) gsh[h] = graph[b * LLG + h];
    __syncthreads();

    float accj[4] = {0,0,0,0};
    float acci[4] = {0,0,0,0};
    for (int k = 0; k < HH; ++k) {
        float wj = W1[k * HH + h];
        float wi = W1[(k + HH) * HH + h];
        #pragma unroll
        for (int r = 0; r < 4; ++r) {
            float nv = nrow[r][k];
            accj[r] = fmaf(nv, wj, accj[r]);
            acci[r] = fmaf(nv, wi, acci[r]);
        }
    }
    float accg = b1[h];
    #pragma unroll
    for (int l = 0; l < LLG; ++l)
        accg = fmaf(gsh[l], W1[(2 * HH + l) * HH + h], accg);

    #pragma unroll
    for (int r = 0; r < 4; ++r) {
        size_t off = (((size_t)b * NN) + r0 + r) * HH + h;
        pj[off]   = accj[r];
        base[off] = acci[r] + accg;
    }
}

// ---------------------------------------------------------------------------
// Kernel 3: fused main. One block per (b,i); 8 waves (512 thr); full j=128.
// LDS: h1s 64 KB + staged edge-f16 16 KB = 80 KB -> 2 blocks/CU (16 waves/CU).
// Wave w owns h-slice [w*32, w*32+32) in GEMM1 and ho-slice likewise in GEMM2.
// GEMM2 keeps mt=8 (16 MFMA per load group) for ILP.
// ---------------------------------------------------------------------------
__global__ __launch_bounds__(512, 4) void fused_msg(
    const float* __restrict__ edge, const float* __restrict__ pj,
    const float* __restrict__ base, const unsigned short* __restrict__ W2T,
    const unsigned short* __restrict__ WeT, const float* __restrict__ b2,
    float* __restrict__ out)
{
    __shared__ unsigned char h1s[NN * HH * 2];   // 64 KB: h1[j][h] f16, swizzled
    __shared__ unsigned char efs[NN * 64 * 2];   // 16 KB: edge[j][f] f16, padded+swizzled
    const int tid  = threadIdx.x;
    const int w    = tid >> 6;         // wave 0..7
    const int lane = tid & 63;
    const int q    = lane >> 4;        // quad 0..3
    const int c    = lane & 15;
    const int bi   = blockIdx.x;       // b*128 + i
    const int b    = bi >> 7;

    const float* eb = edge + (size_t)bi * (NN * FFE);

    // ---- stage edge block -> f16 LDS, row-padded to 64 f16, XOR-swizzled ----
    // rows j: byte = j*128 + (f*2 ^ ((j&7)<<4))
    #pragma unroll
    for (int p = 0; p < 3; ++p) {
        const int e4 = p * 512 + tid;            // float4 index, < 1536
        const int j  = e4 / 12;                  // 12 float4 per 48-float row
        const int f4 = e4 - j * 12;              // 0..11
        const f32x4 x = *reinterpret_cast<const f32x4*>(eb + (e4 << 2));
        unsigned int lo = __builtin_bit_cast(unsigned int,
                            __builtin_amdgcn_cvt_pkrtz(x[0], x[1]));
        unsigned int hi = __builtin_bit_cast(unsigned int,
                            __builtin_amdgcn_cvt_pkrtz(x[2], x[3]));
        const unsigned int off = (unsigned)(j << 7) +
            (((unsigned)(f4 << 3)) ^ ((unsigned)(j & 7) << 4));
        *reinterpret_cast<uint2*>(&efs[off]) = make_uint2(lo, hi);
    }
    {   // zero-fill padded f in [48,64)
        const int j = tid >> 2, g = tid & 3;
        const unsigned int off = (unsigned)(j << 7) +
            (((unsigned)(96 + (g << 3))) ^ ((unsigned)(j & 7) << 4));
        *reinterpret_cast<uint2*>(&efs[off]) = make_uint2(0u, 0u);
    }
    __syncthreads();

    // ------------------ GEMM1: D1[h(32), j(128)] ------------------
    f32x4 acc1[2][8];
    #pragma unroll
    for (int mt = 0; mt < 2; ++mt)
        #pragma unroll
        for (int nt = 0; nt < 8; ++nt) acc1[mt][nt] = f32x4{0.f, 0.f, 0.f, 0.f};

    #pragma unroll
    for (int kk = 0; kk < 2; ++kk) {
        const int koff = (kk << 5) + (q << 3);   // f16-units f offset
        const int fb   = koff << 1;              // byte offset in efs row
        f16x8 af[2];
        #pragma unroll
        for (int mt = 0; mt < 2; ++mt) {
            const int row = (w << 5) + (mt << 4) + c;       // h
            af[mt] = *reinterpret_cast<const f16x8*>(WeT + (row << 6) + koff);
        }
        #pragma unroll
        for (int nt = 0; nt < 8; ++nt) {
            const int j = (nt << 4) + c;
            const f16x8 bf = *reinterpret_cast<const f16x8*>(
                &efs[(unsigned)(j << 7) +
                     (((unsigned)fb) ^ ((unsigned)(j & 7) << 4))]);
            #pragma unroll
            for (int mt = 0; mt < 2; ++mt)
                acc1[mt][nt] = __builtin_amdgcn_mfma_f32_16x16x32_f16(
                    af[mt], bf, acc1[mt][nt], 0, 0, 0);
        }
    }

    // epilogue 1: z1 -> silu -> f16 -> h1s (swizzle: byte ^= (j&7)<<4)
    #pragma unroll
    for (int mt = 0; mt < 2; ++mt) {
        const int h0 = (w << 5) + (mt << 4) + (q << 2);
        const f32x4 bb = *reinterpret_cast<const f32x4*>(
            base + ((size_t)bi << 8) + h0);
        #pragma unroll
        for (int nt = 0; nt < 8; ++nt) {
            const int jc = (nt << 4) + c;
            const f32x4 pjv = *reinterpret_cast<const f32x4*>(
                pj + (((size_t)b << 7) + jc) * HH + h0);
            float s0 = fast_silu(acc1[mt][nt][0] + bb[0] + pjv[0]);
            float s1 = fast_silu(acc1[mt][nt][1] + bb[1] + pjv[1]);
            float s2 = fast_silu(acc1[mt][nt][2] + bb[2] + pjv[2]);
            float s3 = fast_silu(acc1[mt][nt][3] + bb[3] + pjv[3]);
            unsigned int lo = __builtin_bit_cast(unsigned int,
                                __builtin_amdgcn_cvt_pkrtz(s0, s1));
            unsigned int hi = __builtin_bit_cast(unsigned int,
                                __builtin_amdgcn_cvt_pkrtz(s2, s3));
            const unsigned int off = (unsigned)(jc << 9) +
                (((unsigned)(h0 << 1)) ^ ((unsigned)(jc & 7) << 4));
            *reinterpret_cast<uint2*>(&h1s[off]) = make_uint2(lo, hi);
        }
    }
    __syncthreads();

    // ------------------ GEMM2: D2[jc(128), ho(32)] ------------------
    f32x4 acc2[8][2];
    #pragma unroll
    for (int mt = 0; mt < 8; ++mt)
        #pragma unroll
        for (int nt = 0; nt < 2; ++nt) acc2[mt][nt] = f32x4{0.f, 0.f, 0.f, 0.f};

    #pragma unroll 2
    for (int kk = 0; kk < 8; ++kk) {
        const int kb = (kk << 6) + (q << 4);     // byte offset of k-slice
        f16x8 bw[2];
        #pragma unroll
        for (int nt = 0; nt < 2; ++nt) {
            const int ho = (w << 5) + (nt << 4) + c;
            bw[nt] = *reinterpret_cast<const f16x8*>(
                W2T + (ho << 8) + (kk << 5) + (q << 3));
        }
        #pragma unroll
        for (int g = 0; g < 2; ++g) {
            f16x8 a2[4];
            #pragma unroll
            for (int m = 0; m < 4; ++m) {
                const int jc = ((g << 2) + m) * 16 + c;
                const unsigned int off = (unsigned)(jc << 9) +
                    (((unsigned)kb) ^ ((unsigned)(jc & 7) << 4));
                a2[m] = *reinterpret_cast<const f16x8*>(&h1s[off]);
            }
            #pragma unroll
            for (int m = 0; m < 4; ++m)
                #pragma unroll
                for (int nt = 0; nt < 2; ++nt)
                    acc2[(g << 2) + m][nt] = __builtin_amdgcn_mfma_f32_16x16x32_f16(
                        a2[m], bw[nt], acc2[(g << 2) + m][nt], 0, 0, 0);
        }
    }

    // epilogue 2: silu + j-sum, butterfly across quads, store
    float b2v[2];
    #pragma unroll
    for (int nt = 0; nt < 2; ++nt) b2v[nt] = b2[(w << 5) + (nt << 4) + c];

    float s[2] = {0.f, 0.f};
    #pragma unroll
    for (int nt = 0; nt < 2; ++nt)
        #pragma unroll
        for (int mt = 0; mt < 8; ++mt)
            #pragma unroll
            for (int r = 0; r < 4; ++r)
                s[nt] += fast_silu(acc2[mt][nt][r] + b2v[nt]);

    #pragma unroll
    for (int nt = 0; nt < 2; ++nt) {
        s[nt] += __shfl_xor(s[nt], 16);
        s[nt] += __shfl_xor(s[nt], 32);
    }
    if (q < 2)
        out[((size_t)bi << 8) + (w << 5) + (q << 4) + c] = s[q] * 0.0078125f;
}

// ---------------------------------------------------------------------------
extern "C" void kernel_launch(void* const* d_in, const int* in_sizes, int n_in,
                              void* d_out, int out_size, void* d_ws, size_t ws_size,
                              hipStream_t stream)
{
    const float* node  = (const float*)d_in[0];
    const float* edge  = (const float*)d_in[1];
    const float* graph = (const float*)d_in[2];
    const float* W1    = (const float*)d_in[3];
    const float* b1    = (const float*)d_in[4];
    const float* W2    = (const float*)d_in[5];
    const float* b2    = (const float*)d_in[6];
    float* out = (float*)d_out;

    char* ws = (char*)d_ws;
    unsigned short* W2T = (unsigned short*)ws;              // 131072 B
    unsigned short* WeT = (unsigned short*)(ws + 131072);   //  32768 B
    float* pj   = (float*)(ws + 163840);                    // 2 MB
    float* base = (float*)(ws + 163840 + 2097152);          // 2 MB

    pre_w     <<<256, 256, 0, stream>>>(W1, W2, W2T, WeT);
    pre_pjbase<<<512, 256, 0, stream>>>(node, graph, W1, b1, pj, base);
    fused_msg <<<BSZ * NN, 512, 0, stream>>>(edge, pj, base, W2T, WeT, b2, out);
}